// Round 12
// baseline (665.214 us; speedup 1.0000x reference)
//
#include <hip/hip_runtime.h>

#define HCDIM 292
#define NHEAD 4
#define CDIM 73
#define SLOTS 5
#define NPERM 320
#define BN_EPS 1e-5f
#define LOG2E 1.44269504f

using u16x8 = __attribute__((ext_vector_type(8))) unsigned short;
using f32x4 = __attribute__((ext_vector_type(4))) float;   // MFMA acc
using u16x4 = __attribute__((ext_vector_type(4))) unsigned short;
using hf2   = __attribute__((ext_vector_type(2))) _Float16;  // arithmetic type
using v2h   = __attribute__((ext_vector_type(2))) __fp16;    // builtin boundary
using v8h   = __attribute__((ext_vector_type(8))) __fp16;    // MFMA frag

__device__ inline v2h pkrtz(float a, float b) {              // 2xf32 -> packed f16
  return __builtin_amdgcn_cvt_pkrtz(a, b);
}
__device__ inline float fdot2(hf2 a, hf2 b, float c) {
  return __builtin_amdgcn_fdot2(__builtin_bit_cast(v2h, a),
                                __builtin_bit_cast(v2h, b), c, false);
}
__device__ inline ushort f2h(float f) {
  _Float16 h = (_Float16)f;
  return __builtin_bit_cast(ushort, h);
}
__device__ inline float h2f(ushort v) {
  return (float)__builtin_bit_cast(_Float16, v);
}
__device__ inline hf2 habs2(hf2 a) {
  unsigned u = __builtin_bit_cast(unsigned, a) & 0x7fff7fffu;
  return __builtin_bit_cast(hf2, u);
}

// permuted slot p -> original feature index (h*73+c); valid=false for 28 dead slots
__device__ inline int perm2feat(int p, bool& valid) {
  int h, c;
  if (p < 256) {
    h = p >> 6;
    c = ((p & 3) << 4) | ((p >> 2) & 15);
    valid = true;
  } else {
    int q = p - 256;
    h = q >> 4;
    c = 64 + (q & 15);
    valid = (q & 15) < (CDIM - 64);
  }
  return h * CDIM + c;
}

// ======================= weight / vector prep =======================
__global__ void k_wperm(const float* __restrict__ W, const float* __restrict__ b,
                        ushort* __restrict__ Wp, float* __restrict__ pb,
                        int Kin, int Kpad, int kperm) {
  int p = blockIdx.x, t = threadIdx.x;
  bool pv;
  int gn = perm2feat(p, pv);
  int gk = t;
  bool kv = t < Kin;
  if (kperm) { bool v2; gk = perm2feat(t, v2); kv = v2; }
  ushort v = 0;
  if (pv && kv) v = f2h(W[(size_t)gn * Kin + gk]);
  Wp[(size_t)p * Kpad + t] = v;
  if (t == 0) pb[p] = pv ? b[gn] : 0.f;
}

// o layout: [att1|b1|att2|b2|gamma|beta|Wc0|Wc1] x 320 (fp32, permuted, dead->0)
__global__ void k_vecperm(const float* __restrict__ att1, const float* __restrict__ b1,
                          const float* __restrict__ att2, const float* __restrict__ b2,
                          const float* __restrict__ gamma, const float* __restrict__ beta,
                          const float* __restrict__ Wc, float* __restrict__ o) {
  int p = threadIdx.x, w = blockIdx.x;
  bool pv;
  int gn = perm2feat(p, pv);
  const float* src;
  switch (w) {
    case 0: src = att1; break;
    case 1: src = b1; break;
    case 2: src = att2; break;
    case 3: src = b2; break;
    case 4: src = gamma; break;
    case 5: src = beta; break;
    case 6: src = Wc; break;
    default: src = Wc + HCDIM; break;
  }
  o[w * NPERM + p] = pv ? src[gn] : 0.f;
}

// ======================= CSR build =======================
__global__ void k_hist(const int* __restrict__ dst, int* __restrict__ deg, int E) {
  int i = blockIdx.x * blockDim.x + threadIdx.x;
  if (i < E) atomicAdd(&deg[dst[i]], 1);
}

__global__ __launch_bounds__(256) void k_block_sum(const int* __restrict__ deg,
                                                   int* __restrict__ bsum, int n) {
  __shared__ int s[256];
  int i = blockIdx.x * 256 + threadIdx.x;
  s[threadIdx.x] = (i < n) ? deg[i] : 0;
  __syncthreads();
  for (int off = 128; off > 0; off >>= 1) {
    if (threadIdx.x < off) s[threadIdx.x] += s[threadIdx.x + off];
    __syncthreads();
  }
  if (threadIdx.x == 0) bsum[blockIdx.x] = s[0];
}

__global__ __launch_bounds__(256) void k_scan_small(const int* __restrict__ bsum,
                                                    int* __restrict__ boff, int G) {
  __shared__ int s[256];
  int t = threadIdx.x;
  int v = (t < G) ? bsum[t] : 0;
  s[t] = v;
  __syncthreads();
  for (int off = 1; off < 256; off <<= 1) {
    int tv = (t >= off) ? s[t - off] : 0;
    __syncthreads();
    s[t] += tv;
    __syncthreads();
  }
  if (t < G) boff[t] = s[t] - v;
}

__global__ __launch_bounds__(256) void k_scan_final(const int* __restrict__ deg,
                                                    const int* __restrict__ boff,
                                                    int* __restrict__ row_ptr,
                                                    int* __restrict__ cursor,
                                                    int n, int E) {
  __shared__ int s[256];
  int t = threadIdx.x;
  int i = blockIdx.x * 256 + t;
  int v = (i < n) ? deg[i] : 0;
  s[t] = v;
  __syncthreads();
  for (int off = 1; off < 256; off <<= 1) {
    int tv = (t >= off) ? s[t - off] : 0;
    __syncthreads();
    s[t] += tv;
    __syncthreads();
  }
  if (i < n) {
    int rp = boff[blockIdx.x] + s[t] - v;
    row_ptr[i] = rp;
    cursor[i] = rp;
  }
  if (i == 0) row_ptr[n] = E;
}

__global__ void k_csr_fill(const int* __restrict__ srcs, const int* __restrict__ dsts,
                           int* __restrict__ cursor, int* __restrict__ csr_src, int E) {
  int i = blockIdx.x * blockDim.x + threadIdx.x;
  if (i < E) {
    int pos = atomicAdd(&cursor[dsts[i]], 1);
    csr_src[pos] = srcs[i];
  }
}

// ======================= B-in-LDS GEMM, M-streaming (f16) =======================
template <bool CVT>
__device__ inline void load_af(const char* const (&Ar)[4], int koff, int quad,
                               v8h (&af)[4]) {
#pragma unroll
  for (int i = 0; i < 4; ++i) {
    if (CVT) {
      const float* p = (const float*)Ar[i] + koff + quad * 8;
      float4 f0 = *(const float4*)p;
      float4 f1 = *(const float4*)(p + 4);
      union { v2h h[4]; v8h v; } u;
      u.h[0] = pkrtz(f0.x, f0.y);
      u.h[1] = pkrtz(f0.z, f0.w);
      u.h[2] = pkrtz(f1.x, f1.y);
      u.h[3] = pkrtz(f1.z, f1.w);
      af[i] = u.v;
    } else {
      af[i] = *(const v8h*)((const ushort*)Ar[i] + koff + quad * 8);
    }
  }
}

template <int KS, bool CVT>
__global__ __launch_bounds__(256) void k_gemm_blds(
    const void* __restrict__ Av, const ushort* __restrict__ Wb,
    const float* __restrict__ pb, ushort* __restrict__ o0,
    ushort* __restrict__ o1, int M, int miters) {
  constexpr int KSTEPS = KS / 32;
  constexpr int BSTR = KS + 8;
  __shared__ ushort Bs[80 * BSTR];
  int b = blockIdx.x;
  int mlo = b & 7, ct = (b >> 3) & 7, mhi = b >> 6;
  int mc = mlo + 8 * mhi;
  ushort* out = (ct < 4) ? o0 : o1;
  const int colbase = (ct & 3) * 80;
  const int tid = threadIdx.x;
  const int wave = tid >> 6, lane = tid & 63;
  const int quad = lane >> 4, lr = lane & 15;
  const int esz = CVT ? 4 : 2;

  for (int idx = tid; idx < 80 * (KS / 8); idx += 256) {
    int r = idx / (KS / 8), c8 = idx - r * (KS / 8);
    *(u16x8*)(Bs + r * BSTR + c8 * 8) =
        *(const u16x8*)(Wb + (size_t)(ct * 80 + r) * KS + c8 * 8);
  }
  __syncthreads();

  const ushort* bp[5];
#pragma unroll
  for (int i = 0; i < 5; ++i) bp[i] = Bs + (i * 16 + lr) * BSTR;

  float4 pbv[5];
#pragma unroll
  for (int ni = 0; ni < 5; ++ni)
    pbv[ni] = *(const float4*)(pb + ct * 80 + ni * 16 + quad * 4);

  for (int it = mc; it < miters; it += 64) {
    int mbase = it * 256 + wave * 64;
    const char* Ar[4];
#pragma unroll
    for (int i = 0; i < 4; ++i) {
      int ar = mbase + i * 16 + lr;
      if (ar >= M) ar = M - 1;
      Ar[i] = (const char*)Av + (size_t)ar * KS * esz;
    }
    f32x4 acc[4][5] = {};
    v8h afb[2][4];
    load_af<CVT>(Ar, 0, quad, afb[0]);
#pragma unroll
    for (int s = 0; s < KSTEPS; ++s) {
      if (s + 1 < KSTEPS) load_af<CVT>(Ar, (s + 1) * 32, quad, afb[(s + 1) & 1]);
      v8h bf[5];
#pragma unroll
      for (int i = 0; i < 5; ++i)
        bf[i] = *(const v8h*)(bp[i] + s * 32 + quad * 8);
#pragma unroll
      for (int ni = 0; ni < 5; ++ni)
#pragma unroll
        for (int mi = 0; mi < 4; ++mi)   // bf first: acc regs index 4 consecutive n
          acc[mi][ni] = __builtin_amdgcn_mfma_f32_16x16x32_f16(
              bf[ni], afb[s & 1][mi], acc[mi][ni], 0, 0, 0);
    }
#pragma unroll
    for (int mi = 0; mi < 4; ++mi) {
      int gm = mbase + mi * 16 + lr;
      if (gm >= M) continue;
      ushort* orow = out + (size_t)gm * NPERM + colbase + quad * 4;
#pragma unroll
      for (int ni = 0; ni < 5; ++ni) {
        union { v2h h[2]; u16x4 o; } u;
        u.h[0] = pkrtz(acc[mi][ni][0] + pbv[ni].x, acc[mi][ni][1] + pbv[ni].y);
        u.h[1] = pkrtz(acc[mi][ni][2] + pbv[ni].z, acc[mi][ni][3] + pbv[ni].w);
        *(u16x4*)(orow + ni * 16) = u.o;
      }
    }
  }
}

// ======================= per-node pl (xl attention pre-dot, f16 dot2) =======================
// pl = 1.5 * sum(xl * attC) reduced over head-group, attC = 0.4*log2(e)*att
__global__ __launch_bounds__(256) void k_pre(const ushort* __restrict__ xl,
                                             const float* __restrict__ attp,
                                             float* __restrict__ pl, int n) {
  int wave = threadIdx.x >> 6, lane = threadIdx.x & 63;
  int d = blockIdx.x * 4 + wave;
  if (d >= n) return;
  int hgrp = lane >> 4, li = lane & 15;
  const float C = 0.4f * LOG2E;
  float4 a4 = *(const float4*)(attp + lane * 4);
  hf2 av01{(_Float16)(C * a4.x), (_Float16)(C * a4.y)};
  hf2 av23{(_Float16)(C * a4.z), (_Float16)(C * a4.w)};
  hf2 av5{(_Float16)(C * attp[256 + lane]), (_Float16)0.f};

  uint2 cc = *(const uint2*)(xl + (size_t)d * NPERM + lane * 4);
  ushort c5 = xl[(size_t)d * NPERM + 256 + lane];
  hf2 c01 = __builtin_bit_cast(hf2, cc.x);
  hf2 c23 = __builtin_bit_cast(hf2, cc.y);
  hf2 c5h{__builtin_bit_cast(_Float16, c5), (_Float16)0.f};

  float Ta = fdot2(c01, av01, fdot2(c23, av23, fdot2(c5h, av5, 0.f)));
#pragma unroll
  for (int off = 1; off < 16; off <<= 1) Ta += __shfl_xor(Ta, off, 64);
  if (li == 0) pl[d * 4 + hgrp] = 1.5f * Ta;
}

// ======================= fused GATv2 attention (4-deep edge pipeline) =======================
__global__ __launch_bounds__(256) void k_agg(const ushort* __restrict__ xl,
                                             const ushort* __restrict__ xr,
                                             const float* __restrict__ pl,
                                             const int* __restrict__ csr_src,
                                             const int* __restrict__ row_ptr,
                                             const float* __restrict__ attp,
                                             const float* __restrict__ bp,
                                             ushort* __restrict__ out, int n) {
  int wave = threadIdx.x >> 6, lane = threadIdx.x & 63;
  int d = blockIdx.x * 4 + wave;
  if (d >= n) return;
  int hgrp = lane >> 4;
  int start = __builtin_amdgcn_readfirstlane(row_ptr[d]);
  int end = __builtin_amdgcn_readfirstlane(row_ptr[d + 1]);

  float4 bp4 = *(const float4*)(bp + lane * 4);
  float bp5 = bp[256 + lane];

  if (start >= end) {                      // isolated node -> bias only
    union { v2h h[2]; u16x4 o; } u;
    u.h[0] = pkrtz(bp4.x, bp4.y);
    u.h[1] = pkrtz(bp4.z, bp4.w);
    *(u16x4*)(out + (size_t)d * NPERM + lane * 4) = u.o;
    out[(size_t)d * NPERM + 256 + lane] = f2h(bp5);
    return;
  }

  const float C = 0.4f * LOG2E;
  float4 at4 = *(const float4*)(attp + lane * 4);
  hf2 av01{(_Float16)(C * at4.x), (_Float16)(C * at4.y)};
  hf2 av23{(_Float16)(C * at4.z), (_Float16)(C * at4.w)};
  hf2 av5{(_Float16)(C * attp[256 + lane]), (_Float16)0.f};

  hf2 xr01, xr23, xr5;
  {
    uint2 rr = *(const uint2*)(xr + (size_t)d * NPERM + lane * 4);
    xr01 = __builtin_bit_cast(hf2, rr.x);
    xr23 = __builtin_bit_cast(hf2, rr.y);
    xr5 = hf2{__builtin_bit_cast(_Float16, xr[(size_t)d * NPERM + 256 + lane]),
              (_Float16)0.f};
  }
  // prv = 1.5 * sum(xr*attC) (log2-domain like pl)
  float Tb = fdot2(xr01, av01, fdot2(xr23, av23, fdot2(xr5, av5, 0.f)));
  Tb += __shfl_xor(Tb, 1, 64);
  Tb += __shfl_xor(Tb, 2, 64);
  Tb += __shfl_xor(Tb, 4, 64);
  Tb += __shfl_xor(Tb, 8, 64);
  float prv = 1.5f * Tb;
  float acc[SLOTS] = {};
  float den = 0.f;
  int dg = end - start;
  int nfull = dg >> 2;
  int rem = dg & 3;

  // 4-slot edge pipeline: slots hold edges e..e+3 (clamped)
  uint2 s8[4];
  ushort s1[4];
  float sp[4];
#pragma unroll
  for (int k = 0; k < 4; ++k) {
    int e = start + k;
    if (e > end - 1) e = end - 1;
    int s = __builtin_amdgcn_readfirstlane(csr_src[e]);
    s8[k] = *(const uint2*)(xl + (size_t)s * NPERM + lane * 4);
    s1[k] = xl[(size_t)s * NPERM + 256 + lane];
    sp[k] = pl[s * 4 + hgrp];
  }

  for (int g = 0; g < nfull; ++g) {
    int ebase = start + g * 4 + 4;
    uint2 n8[4];
    ushort n1[4];
    float np[4];
#pragma unroll
    for (int k = 0; k < 4; ++k) {
      int e = ebase + k;
      if (e > end - 1) e = end - 1;
      int s = __builtin_amdgcn_readfirstlane(csr_src[e]);
      n8[k] = *(const uint2*)(xl + (size_t)s * NPERM + lane * 4);
      n1[k] = xl[(size_t)s * NPERM + 256 + lane];
      np[k] = pl[s * 4 + hgrp];
    }

    hf2 x01[4], x23[4], x5[4];
    float T[4];
#pragma unroll
    for (int k = 0; k < 4; ++k) {
      x01[k] = __builtin_bit_cast(hf2, s8[k].x);
      x23[k] = __builtin_bit_cast(hf2, s8[k].y);
      x5[k] = hf2{__builtin_bit_cast(_Float16, s1[k]), (_Float16)0.f};
      T[k] = fdot2(habs2(x01[k] + xr01), av01,
             fdot2(habs2(x23[k] + xr23), av23,
             fdot2(habs2(x5[k] + xr5), av5, 0.f)));
    }
#pragma unroll
    for (int off = 1; off <= 8; off <<= 1) {
#pragma unroll
      for (int k = 0; k < 4; ++k) T[k] += __shfl_xor(T[k], off, 64);
    }
    float w[4];
#pragma unroll
    for (int k = 0; k < 4; ++k) {
      w[k] = exp2f(fminf(T[k] + sp[k] + prv, 80.f));
      den += w[k];
    }
#pragma unroll
    for (int k = 0; k < 4; ++k) {
      acc[0] = fmaf(w[k], (float)x01[k][0], acc[0]);
      acc[1] = fmaf(w[k], (float)x01[k][1], acc[1]);
      acc[2] = fmaf(w[k], (float)x23[k][0], acc[2]);
      acc[3] = fmaf(w[k], (float)x23[k][1], acc[3]);
      acc[4] = fmaf(w[k], (float)x5[k][0], acc[4]);
    }
#pragma unroll
    for (int k = 0; k < 4; ++k) { s8[k] = n8[k]; s1[k] = n1[k]; sp[k] = np[k]; }
  }

  // tail: rem edges live in slots 0..rem-1
  for (int t = 0; t < rem; ++t) {
    hf2 x01 = __builtin_bit_cast(hf2, s8[t].x);
    hf2 x23 = __builtin_bit_cast(hf2, s8[t].y);
    hf2 x5{__builtin_bit_cast(_Float16, s1[t]), (_Float16)0.f};
    float T = fdot2(habs2(x01 + xr01), av01,
              fdot2(habs2(x23 + xr23), av23,
              fdot2(habs2(x5 + xr5), av5, 0.f)));
    T += __shfl_xor(T, 1, 64);
    T += __shfl_xor(T, 2, 64);
    T += __shfl_xor(T, 4, 64);
    T += __shfl_xor(T, 8, 64);
    float w = exp2f(fminf(T + sp[t] + prv, 80.f));
    den += w;
    acc[0] = fmaf(w, (float)x01[0], acc[0]);
    acc[1] = fmaf(w, (float)x01[1], acc[1]);
    acc[2] = fmaf(w, (float)x23[0], acc[2]);
    acc[3] = fmaf(w, (float)x23[1], acc[3]);
    acc[4] = fmaf(w, (float)x5[0], acc[4]);
  }

  float inv = 1.f / (den + 1e-16f);
  union { v2h h[2]; u16x4 o; } u;
  u.h[0] = pkrtz(fmaf(acc[0], inv, bp4.x), fmaf(acc[1], inv, bp4.y));
  u.h[1] = pkrtz(fmaf(acc[2], inv, bp4.z), fmaf(acc[3], inv, bp4.w));
  *(u16x4*)(out + (size_t)d * NPERM + lane * 4) = u.o;
  out[(size_t)d * NPERM + 256 + lane] = f2h(fmaf(acc[4], inv, bp5));
}

// ======================= BatchNorm (permuted f16 h) =======================
__global__ __launch_bounds__(320) void k_bn_reduce(const ushort* __restrict__ h,
                                                   float* __restrict__ colsum,
                                                   float* __restrict__ colsq,
                                                   int n, int rows_per_block) {
  int c = threadIdx.x;
  int r0 = blockIdx.x * rows_per_block;
  int r1 = min(r0 + rows_per_block, n);
  float s = 0.f, s2 = 0.f;
  for (int r = r0; r < r1; ++r) {
    float v = h2f(h[(size_t)r * NPERM + c]);
    s += v;
    s2 += v * v;
  }
  atomicAdd(&colsum[c], s);
  atomicAdd(&colsq[c], s2);
}

__global__ void k_bn_coef(float* __restrict__ colsum, float* __restrict__ colsq,
                          const float* __restrict__ gp, const float* __restrict__ bp,
                          float invN) {
  int c = threadIdx.x + blockIdx.x * blockDim.x;
  if (c >= NPERM) return;
  float mu = colsum[c] * invN;
  float var = colsq[c] * invN - mu * mu;
  float scale = rsqrtf(var + BN_EPS) * gp[c];
  colsum[c] = scale;
  colsq[c] = bp[c] - mu * scale;
}

// BN + leaky-relu: h f16 -> abuf f16 (layer-2 GEMM A)
__global__ void k_bn_apply_bf(const ushort* __restrict__ h,
                              const float* __restrict__ scale,
                              const float* __restrict__ shift,
                              ushort* __restrict__ outb, int total8) {
  int i = blockIdx.x * blockDim.x + threadIdx.x;
  if (i >= total8) return;
  int cg = i - (i / 40) * 40;
  u16x8 v = *(const u16x8*)(h + (size_t)i * 8);
  float f[8];
#pragma unroll
  for (int k = 0; k < 8; ++k) {
    int c = cg * 8 + k;
    float t = fmaf(h2f(v[k]), scale[c], shift[c]);
    f[k] = (t > 0.f) ? t : 0.01f * t;
  }
  union { v2h h4[4]; u16x8 o; } u;
#pragma unroll
  for (int k = 0; k < 4; ++k)
    u.h4[k] = pkrtz(f[2 * k], f[2 * k + 1]);
  *(u16x8*)(outb + (size_t)i * 8) = u.o;
}

// ======================= fused BN + leaky-relu + classifier =======================
__global__ __launch_bounds__(256) void k_bn_classifier(
    const ushort* __restrict__ h, const float* __restrict__ scale,
    const float* __restrict__ shift, const float* __restrict__ wc0,
    const float* __restrict__ wc1, const float* __restrict__ bc,
    float* __restrict__ out, int n) {
  int wave = threadIdx.x >> 6, lane = threadIdx.x & 63;
  int r = blockIdx.x * 4 + wave;
  if (r >= n) return;
  float a0 = 0.f, a1 = 0.f;
#pragma unroll
  for (int k = 0; k < SLOTS; ++k) {
    int slot = lane + 64 * k;
    float v = fmaf(h2f(h[(size_t)r * NPERM + slot]), scale[slot], shift[slot]);
    v = (v > 0.f) ? v : 0.01f * v;
    a0 = fmaf(v, wc0[slot], a0);
    a1 = fmaf(v, wc1[slot], a1);
  }
#pragma unroll
  for (int off = 32; off > 0; off >>= 1) {
    a0 += __shfl_xor(a0, off, 64);
    a1 += __shfl_xor(a1, off, 64);
  }
  if (lane == 0) {
    out[(size_t)2 * r] = a0 + bc[0];
    out[(size_t)2 * r + 1] = a1 + bc[1];
  }
}

// ======================= host launch =======================
extern "C" void kernel_launch(void* const* d_in, const int* in_sizes, int n_in,
                              void* d_out, int out_size, void* d_ws, size_t ws_size,
                              hipStream_t stream) {
  const float* x      = (const float*)d_in[0];
  const int*   eidx   = (const int*)d_in[1];
  const float* Wl1    = (const float*)d_in[2];
  const float* bl1    = (const float*)d_in[3];
  const float* Wr1    = (const float*)d_in[4];
  const float* br1    = (const float*)d_in[5];
  const float* att1   = (const float*)d_in[6];
  const float* b1     = (const float*)d_in[7];
  const float* Wl2    = (const float*)d_in[8];
  const float* bl2    = (const float*)d_in[9];
  const float* Wr2    = (const float*)d_in[10];
  const float* br2    = (const float*)d_in[11];
  const float* att2   = (const float*)d_in[12];
  const float* b2     = (const float*)d_in[13];
  const float* gamma  = (const float*)d_in[14];
  const float* beta   = (const float*)d_in[15];
  const float* Wc     = (const float*)d_in[16];
  const float* bc     = (const float*)d_in[17];
  float* out = (float*)d_out;

  const int FIN = 128;
  const int N = in_sizes[0] / FIN;   // 50000
  const int E = in_sizes[1] / 2;     // 800000

  const int* src = eidx;
  const int* dst = eidx + E;

  // ---- workspace layout (16B-aligned) ----
  ushort* h      = (ushort*)d_ws;                 // N*320 f16 permuted
  ushort* xl     = h + (size_t)N * NPERM;         // N*320
  ushort* xr     = xl + (size_t)N * NPERM;        // N*320
  ushort* abuf   = xr + (size_t)N * NPERM;        // N*320 (layer-2 GEMM A)
  ushort* wb     = abuf + (size_t)N * NPERM;      // 640*320 combined Wl|Wr
  float* pb      = (float*)(wb + (size_t)2 * NPERM * NPERM);  // 640
  float* vecp    = pb + 2 * NPERM;                // 8*320
  float* pl      = vecp + 8 * NPERM;              // N*4
  float* colsum  = pl + (size_t)N * NHEAD;        // 320 (-> scale)
  float* colsq   = colsum + NPERM;                // 320 (-> shift)
  int* deg       = (int*)(colsq + NPERM);
  int* row_ptr   = deg + N;                       // N+1
  int* cursor    = row_ptr + N + 1;
  int* bsum      = cursor + N;                    // 256
  int* boff      = bsum + 256;                    // 256
  int* csr_src   = boff + 256;                    // E

  const int G = (N + 255) / 256;
  const int EB = (E + 255) / 256;
  const int AGGB = (N + 3) / 4;
  const int MITERS = (N + 255) / 256;
  const int GEMMB = 512;

  const float* att1p = vecp;
  const float* b1p   = vecp + NPERM;
  const float* att2p = vecp + 2 * NPERM;
  const float* b2p   = vecp + 3 * NPERM;
  const float* gp    = vecp + 4 * NPERM;
  const float* btp   = vecp + 5 * NPERM;
  const float* wc0   = vecp + 6 * NPERM;
  const float* wc1   = vecp + 7 * NPERM;

  // ---- CSR build ----
  hipMemsetAsync(deg, 0, (size_t)N * sizeof(int), stream);
  k_hist<<<EB, 256, 0, stream>>>(dst, deg, E);
  k_block_sum<<<G, 256, 0, stream>>>(deg, bsum, N);
  k_scan_small<<<1, 256, 0, stream>>>(bsum, boff, G);
  k_scan_final<<<G, 256, 0, stream>>>(deg, boff, row_ptr, cursor, N, E);
  k_csr_fill<<<EB, 256, 0, stream>>>(src, dst, cursor, csr_src, E);

  k_vecperm<<<8, NPERM, 0, stream>>>(att1, b1, att2, b2, gamma, beta, Wc, vecp);

  // ---- layer 1 (A = x fp32, converted in-register) ----
  k_wperm<<<NPERM, FIN, 0, stream>>>(Wl1, bl1, wb, pb, FIN, FIN, 0);
  k_wperm<<<NPERM, FIN, 0, stream>>>(Wr1, br1, wb + (size_t)NPERM * FIN, pb + NPERM,
                                     FIN, FIN, 0);
  k_gemm_blds<FIN, true><<<GEMMB, 256, 0, stream>>>((const void*)x, wb, pb,
                                                    xl, xr, N, MITERS);
  k_pre<<<AGGB, 256, 0, stream>>>(xl, att1p, pl, N);
  k_agg<<<AGGB, 256, 0, stream>>>(xl, xr, pl, csr_src, row_ptr, att1p, b1p, h, N);

  const int RPB = (N + 255) / 256;
  hipMemsetAsync(colsum, 0, 2 * NPERM * sizeof(float), stream);
  k_bn_reduce<<<256, NPERM, 0, stream>>>(h, colsum, colsq, N, RPB);
  k_bn_coef<<<2, 160, 0, stream>>>(colsum, colsq, gp, btp, 1.f / (float)N);
  k_bn_apply_bf<<<(N * 40 + 255) / 256, 256, 0, stream>>>(h, colsum, colsq, abuf,
                                                          N * 40);

  // ---- layer 2 (K permuted to match permuted-native abuf) ----
  k_wperm<<<NPERM, NPERM, 0, stream>>>(Wl2, bl2, wb, pb, HCDIM, NPERM, 1);
  k_wperm<<<NPERM, NPERM, 0, stream>>>(Wr2, br2, wb + (size_t)NPERM * NPERM,
                                       pb + NPERM, HCDIM, NPERM, 1);
  k_gemm_blds<NPERM, false><<<GEMMB, 256, 0, stream>>>((const void*)abuf, wb, pb,
                                                       xl, xr, N, MITERS);
  k_pre<<<AGGB, 256, 0, stream>>>(xl, att2p, pl, N);
  k_agg<<<AGGB, 256, 0, stream>>>(xl, xr, pl, csr_src, row_ptr, att2p, b2p, h, N);

  hipMemsetAsync(colsum, 0, 2 * NPERM * sizeof(float), stream);
  k_bn_reduce<<<256, NPERM, 0, stream>>>(h, colsum, colsq, N, RPB);
  k_bn_coef<<<2, 160, 0, stream>>>(colsum, colsq, gp, btp, 1.f / (float)N);

  // ---- fused BN + classifier ----
  k_bn_classifier<<<AGGB, 256, 0, stream>>>(h, colsum, colsq, wc0, wc1, bc, out, N);
}

// Round 13
// 625.687 us; speedup vs baseline: 1.0632x; 1.0632x over previous
//
#include <hip/hip_runtime.h>

#define HCDIM 292
#define NHEAD 4
#define CDIM 73
#define SLOTS 5
#define NPERM 320
#define BN_EPS 1e-5f
#define LOG2E 1.44269504f

using u16x8 = __attribute__((ext_vector_type(8))) unsigned short;
using f32x4 = __attribute__((ext_vector_type(4))) float;   // MFMA acc
using u16x4 = __attribute__((ext_vector_type(4))) unsigned short;
using hf2   = __attribute__((ext_vector_type(2))) _Float16;  // arithmetic type
using v2h   = __attribute__((ext_vector_type(2))) __fp16;    // builtin boundary
using v8h   = __attribute__((ext_vector_type(8))) __fp16;    // MFMA frag

__device__ inline v2h pkrtz(float a, float b) {              // 2xf32 -> packed f16
  return __builtin_amdgcn_cvt_pkrtz(a, b);
}
__device__ inline float fdot2(hf2 a, hf2 b, float c) {
  return __builtin_amdgcn_fdot2(__builtin_bit_cast(v2h, a),
                                __builtin_bit_cast(v2h, b), c, false);
}
__device__ inline ushort f2h(float f) {
  _Float16 h = (_Float16)f;
  return __builtin_bit_cast(ushort, h);
}
__device__ inline float h2f(ushort v) {
  return (float)__builtin_bit_cast(_Float16, v);
}
__device__ inline hf2 habs2(hf2 a) {
  unsigned u = __builtin_bit_cast(unsigned, a) & 0x7fff7fffu;
  return __builtin_bit_cast(hf2, u);
}

// permuted slot p -> original feature index (h*73+c); valid=false for 28 dead slots
__device__ inline int perm2feat(int p, bool& valid) {
  int h, c;
  if (p < 256) {
    h = p >> 6;
    c = ((p & 3) << 4) | ((p >> 2) & 15);
    valid = true;
  } else {
    int q = p - 256;
    h = q >> 4;
    c = 64 + (q & 15);
    valid = (q & 15) < (CDIM - 64);
  }
  return h * CDIM + c;
}

// ======================= weight / vector prep =======================
__global__ void k_wperm(const float* __restrict__ W, const float* __restrict__ b,
                        ushort* __restrict__ Wp, float* __restrict__ pb,
                        int Kin, int Kpad, int kperm) {
  int p = blockIdx.x, t = threadIdx.x;
  bool pv;
  int gn = perm2feat(p, pv);
  int gk = t;
  bool kv = t < Kin;
  if (kperm) { bool v2; gk = perm2feat(t, v2); kv = v2; }
  ushort v = 0;
  if (pv && kv) v = f2h(W[(size_t)gn * Kin + gk]);
  Wp[(size_t)p * Kpad + t] = v;
  if (t == 0) pb[p] = pv ? b[gn] : 0.f;
}

// o layout: [att1|b1|att2|b2|gamma|beta|Wc0|Wc1] x 320 (fp32, permuted, dead->0)
__global__ void k_vecperm(const float* __restrict__ att1, const float* __restrict__ b1,
                          const float* __restrict__ att2, const float* __restrict__ b2,
                          const float* __restrict__ gamma, const float* __restrict__ beta,
                          const float* __restrict__ Wc, float* __restrict__ o) {
  int p = threadIdx.x, w = blockIdx.x;
  bool pv;
  int gn = perm2feat(p, pv);
  const float* src;
  switch (w) {
    case 0: src = att1; break;
    case 1: src = b1; break;
    case 2: src = att2; break;
    case 3: src = b2; break;
    case 4: src = gamma; break;
    case 5: src = beta; break;
    case 6: src = Wc; break;
    default: src = Wc + HCDIM; break;
  }
  o[w * NPERM + p] = pv ? src[gn] : 0.f;
}

// ======================= CSR build =======================
__global__ void k_hist(const int* __restrict__ dst, int* __restrict__ deg, int E) {
  int i = blockIdx.x * blockDim.x + threadIdx.x;
  if (i < E) atomicAdd(&deg[dst[i]], 1);
}

__global__ __launch_bounds__(256) void k_block_sum(const int* __restrict__ deg,
                                                   int* __restrict__ bsum, int n) {
  __shared__ int s[256];
  int i = blockIdx.x * 256 + threadIdx.x;
  s[threadIdx.x] = (i < n) ? deg[i] : 0;
  __syncthreads();
  for (int off = 128; off > 0; off >>= 1) {
    if (threadIdx.x < off) s[threadIdx.x] += s[threadIdx.x + off];
    __syncthreads();
  }
  if (threadIdx.x == 0) bsum[blockIdx.x] = s[0];
}

__global__ __launch_bounds__(256) void k_scan_small(const int* __restrict__ bsum,
                                                    int* __restrict__ boff, int G) {
  __shared__ int s[256];
  int t = threadIdx.x;
  int v = (t < G) ? bsum[t] : 0;
  s[t] = v;
  __syncthreads();
  for (int off = 1; off < 256; off <<= 1) {
    int tv = (t >= off) ? s[t - off] : 0;
    __syncthreads();
    s[t] += tv;
    __syncthreads();
  }
  if (t < G) boff[t] = s[t] - v;
}

__global__ __launch_bounds__(256) void k_scan_final(const int* __restrict__ deg,
                                                    const int* __restrict__ boff,
                                                    int* __restrict__ row_ptr,
                                                    int* __restrict__ cursor,
                                                    int n, int E) {
  __shared__ int s[256];
  int t = threadIdx.x;
  int i = blockIdx.x * 256 + t;
  int v = (i < n) ? deg[i] : 0;
  s[t] = v;
  __syncthreads();
  for (int off = 1; off < 256; off <<= 1) {
    int tv = (t >= off) ? s[t - off] : 0;
    __syncthreads();
    s[t] += tv;
    __syncthreads();
  }
  if (i < n) {
    int rp = boff[blockIdx.x] + s[t] - v;
    row_ptr[i] = rp;
    cursor[i] = rp;
  }
  if (i == 0) row_ptr[n] = E;
}

__global__ void k_csr_fill(const int* __restrict__ srcs, const int* __restrict__ dsts,
                           int* __restrict__ cursor, int* __restrict__ csr_src, int E) {
  int i = blockIdx.x * blockDim.x + threadIdx.x;
  if (i < E) {
    int pos = atomicAdd(&cursor[dsts[i]], 1);
    csr_src[pos] = srcs[i];
  }
}

// ======================= B-in-LDS GEMM, M-streaming (f16) =======================
template <bool CVT>
__device__ inline void load_af(const char* const (&Ar)[4], int koff, int quad,
                               v8h (&af)[4]) {
#pragma unroll
  for (int i = 0; i < 4; ++i) {
    if (CVT) {
      const float* p = (const float*)Ar[i] + koff + quad * 8;
      float4 f0 = *(const float4*)p;
      float4 f1 = *(const float4*)(p + 4);
      union { v2h h[4]; v8h v; } u;
      u.h[0] = pkrtz(f0.x, f0.y);
      u.h[1] = pkrtz(f0.z, f0.w);
      u.h[2] = pkrtz(f1.x, f1.y);
      u.h[3] = pkrtz(f1.z, f1.w);
      af[i] = u.v;
    } else {
      af[i] = *(const v8h*)((const ushort*)Ar[i] + koff + quad * 8);
    }
  }
}

template <int KS, bool CVT>
__global__ __launch_bounds__(256) void k_gemm_blds(
    const void* __restrict__ Av, const ushort* __restrict__ Wb,
    const float* __restrict__ pb, ushort* __restrict__ o0,
    ushort* __restrict__ o1, int M, int miters) {
  constexpr int KSTEPS = KS / 32;
  constexpr int BSTR = KS + 8;
  __shared__ ushort Bs[80 * BSTR];
  int b = blockIdx.x;
  int mlo = b & 7, ct = (b >> 3) & 7, mhi = b >> 6;
  int mc = mlo + 8 * mhi;
  ushort* out = (ct < 4) ? o0 : o1;
  const int colbase = (ct & 3) * 80;
  const int tid = threadIdx.x;
  const int wave = tid >> 6, lane = tid & 63;
  const int quad = lane >> 4, lr = lane & 15;
  const int esz = CVT ? 4 : 2;

  for (int idx = tid; idx < 80 * (KS / 8); idx += 256) {
    int r = idx / (KS / 8), c8 = idx - r * (KS / 8);
    *(u16x8*)(Bs + r * BSTR + c8 * 8) =
        *(const u16x8*)(Wb + (size_t)(ct * 80 + r) * KS + c8 * 8);
  }
  __syncthreads();

  const ushort* bp[5];
#pragma unroll
  for (int i = 0; i < 5; ++i) bp[i] = Bs + (i * 16 + lr) * BSTR;

  float4 pbv[5];
#pragma unroll
  for (int ni = 0; ni < 5; ++ni)
    pbv[ni] = *(const float4*)(pb + ct * 80 + ni * 16 + quad * 4);

  for (int it = mc; it < miters; it += 64) {
    int mbase = it * 256 + wave * 64;
    const char* Ar[4];
#pragma unroll
    for (int i = 0; i < 4; ++i) {
      int ar = mbase + i * 16 + lr;
      if (ar >= M) ar = M - 1;
      Ar[i] = (const char*)Av + (size_t)ar * KS * esz;
    }
    f32x4 acc[4][5] = {};
    v8h afb[2][4];
    load_af<CVT>(Ar, 0, quad, afb[0]);
#pragma unroll
    for (int s = 0; s < KSTEPS; ++s) {
      if (s + 1 < KSTEPS) load_af<CVT>(Ar, (s + 1) * 32, quad, afb[(s + 1) & 1]);
      v8h bf[5];
#pragma unroll
      for (int i = 0; i < 5; ++i)
        bf[i] = *(const v8h*)(bp[i] + s * 32 + quad * 8);
#pragma unroll
      for (int ni = 0; ni < 5; ++ni)
#pragma unroll
        for (int mi = 0; mi < 4; ++mi)   // bf first: acc regs index 4 consecutive n
          acc[mi][ni] = __builtin_amdgcn_mfma_f32_16x16x32_f16(
              bf[ni], afb[s & 1][mi], acc[mi][ni], 0, 0, 0);
    }
#pragma unroll
    for (int mi = 0; mi < 4; ++mi) {
      int gm = mbase + mi * 16 + lr;
      if (gm >= M) continue;
      ushort* orow = out + (size_t)gm * NPERM + colbase + quad * 4;
#pragma unroll
      for (int ni = 0; ni < 5; ++ni) {
        union { v2h h[2]; u16x4 o; } u;
        u.h[0] = pkrtz(acc[mi][ni][0] + pbv[ni].x, acc[mi][ni][1] + pbv[ni].y);
        u.h[1] = pkrtz(acc[mi][ni][2] + pbv[ni].z, acc[mi][ni][3] + pbv[ni].w);
        *(u16x4*)(orow + ni * 16) = u.o;
      }
    }
  }
}

// ======================= per-node pl (xl attention pre-dot, f16 dot2) =======================
// pl = 1.5 * sum(xl * attC) reduced over head-group, attC = 0.4*log2(e)*att
__global__ __launch_bounds__(256) void k_pre(const ushort* __restrict__ xl,
                                             const float* __restrict__ attp,
                                             float* __restrict__ pl, int n) {
  int wave = threadIdx.x >> 6, lane = threadIdx.x & 63;
  int d = blockIdx.x * 4 + wave;
  if (d >= n) return;
  int hgrp = lane >> 4, li = lane & 15;
  const float C = 0.4f * LOG2E;
  float4 a4 = *(const float4*)(attp + lane * 4);
  hf2 av01{(_Float16)(C * a4.x), (_Float16)(C * a4.y)};
  hf2 av23{(_Float16)(C * a4.z), (_Float16)(C * a4.w)};
  hf2 av5{(_Float16)(C * attp[256 + lane]), (_Float16)0.f};

  uint2 cc = *(const uint2*)(xl + (size_t)d * NPERM + lane * 4);
  ushort c5 = xl[(size_t)d * NPERM + 256 + lane];
  hf2 c01 = __builtin_bit_cast(hf2, cc.x);
  hf2 c23 = __builtin_bit_cast(hf2, cc.y);
  hf2 c5h{__builtin_bit_cast(_Float16, c5), (_Float16)0.f};

  float Ta = fdot2(c01, av01, fdot2(c23, av23, fdot2(c5h, av5, 0.f)));
#pragma unroll
  for (int off = 1; off < 16; off <<= 1) Ta += __shfl_xor(Ta, off, 64);
  if (li == 0) pl[d * 4 + hgrp] = 1.5f * Ta;
}

// ======================= fused GATv2 attention (4-deep edge pipeline, static idx) ===========
__global__ __launch_bounds__(256) void k_agg(const ushort* __restrict__ xl,
                                             const ushort* __restrict__ xr,
                                             const float* __restrict__ pl,
                                             const int* __restrict__ csr_src,
                                             const int* __restrict__ row_ptr,
                                             const float* __restrict__ attp,
                                             const float* __restrict__ bp,
                                             ushort* __restrict__ out, int n) {
  int wave = threadIdx.x >> 6, lane = threadIdx.x & 63;
  int d = blockIdx.x * 4 + wave;
  if (d >= n) return;
  int hgrp = lane >> 4;
  int start = __builtin_amdgcn_readfirstlane(row_ptr[d]);
  int end = __builtin_amdgcn_readfirstlane(row_ptr[d + 1]);

  float4 bp4 = *(const float4*)(bp + lane * 4);
  float bp5 = bp[256 + lane];

  if (start >= end) {                      // isolated node -> bias only
    union { v2h h[2]; u16x4 o; } u;
    u.h[0] = pkrtz(bp4.x, bp4.y);
    u.h[1] = pkrtz(bp4.z, bp4.w);
    *(u16x4*)(out + (size_t)d * NPERM + lane * 4) = u.o;
    out[(size_t)d * NPERM + 256 + lane] = f2h(bp5);
    return;
  }

  const float C = 0.4f * LOG2E;
  float4 at4 = *(const float4*)(attp + lane * 4);
  hf2 av01{(_Float16)(C * at4.x), (_Float16)(C * at4.y)};
  hf2 av23{(_Float16)(C * at4.z), (_Float16)(C * at4.w)};
  hf2 av5{(_Float16)(C * attp[256 + lane]), (_Float16)0.f};

  hf2 xr01, xr23, xr5;
  {
    uint2 rr = *(const uint2*)(xr + (size_t)d * NPERM + lane * 4);
    xr01 = __builtin_bit_cast(hf2, rr.x);
    xr23 = __builtin_bit_cast(hf2, rr.y);
    xr5 = hf2{__builtin_bit_cast(_Float16, xr[(size_t)d * NPERM + 256 + lane]),
              (_Float16)0.f};
  }
  float Tb = fdot2(xr01, av01, fdot2(xr23, av23, fdot2(xr5, av5, 0.f)));
  Tb += __shfl_xor(Tb, 1, 64);
  Tb += __shfl_xor(Tb, 2, 64);
  Tb += __shfl_xor(Tb, 4, 64);
  Tb += __shfl_xor(Tb, 8, 64);
  float prv = 1.5f * Tb;
  float acc[SLOTS] = {};
  float den = 0.f;
  int dg = end - start;
  int nfull = dg >> 2;
  int rem = dg & 3;

  // 4-slot edge pipeline, ALL indices compile-time (arrays stay in VGPRs)
  uint2 s8[4];
  ushort s1[4];
  float sp[4];
#pragma unroll
  for (int k = 0; k < 4; ++k) {
    int e = start + k;
    if (e > end - 1) e = end - 1;
    int s = __builtin_amdgcn_readfirstlane(csr_src[e]);
    s8[k] = *(const uint2*)(xl + (size_t)s * NPERM + lane * 4);
    s1[k] = xl[(size_t)s * NPERM + 256 + lane];
    sp[k] = pl[s * 4 + hgrp];
  }

  for (int g = 0; g < nfull; ++g) {
    int ebase = start + g * 4 + 4;
    uint2 n8[4];
    ushort n1[4];
    float np[4];
#pragma unroll
    for (int k = 0; k < 4; ++k) {
      int e = ebase + k;
      if (e > end - 1) e = end - 1;
      int s = __builtin_amdgcn_readfirstlane(csr_src[e]);
      n8[k] = *(const uint2*)(xl + (size_t)s * NPERM + lane * 4);
      n1[k] = xl[(size_t)s * NPERM + 256 + lane];
      np[k] = pl[s * 4 + hgrp];
    }

    hf2 x01[4], x23[4], x5[4];
    float T[4];
#pragma unroll
    for (int k = 0; k < 4; ++k) {
      x01[k] = __builtin_bit_cast(hf2, s8[k].x);
      x23[k] = __builtin_bit_cast(hf2, s8[k].y);
      x5[k] = hf2{__builtin_bit_cast(_Float16, s1[k]), (_Float16)0.f};
      T[k] = fdot2(habs2(x01[k] + xr01), av01,
             fdot2(habs2(x23[k] + xr23), av23,
             fdot2(habs2(x5[k] + xr5), av5, 0.f)));
    }
#pragma unroll
    for (int off = 1; off <= 8; off <<= 1) {
#pragma unroll
      for (int k = 0; k < 4; ++k) T[k] += __shfl_xor(T[k], off, 64);
    }
    float w[4];
#pragma unroll
    for (int k = 0; k < 4; ++k) {
      w[k] = exp2f(fminf(T[k] + sp[k] + prv, 80.f));
      den += w[k];
    }
#pragma unroll
    for (int k = 0; k < 4; ++k) {
      acc[0] = fmaf(w[k], (float)x01[k][0], acc[0]);
      acc[1] = fmaf(w[k], (float)x01[k][1], acc[1]);
      acc[2] = fmaf(w[k], (float)x23[k][0], acc[2]);
      acc[3] = fmaf(w[k], (float)x23[k][1], acc[3]);
      acc[4] = fmaf(w[k], (float)x5[k][0], acc[4]);
    }
#pragma unroll
    for (int k = 0; k < 4; ++k) { s8[k] = n8[k]; s1[k] = n1[k]; sp[k] = np[k]; }
  }

  // tail: unrolled + predicated -> static indices only
#pragma unroll
  for (int k = 0; k < 3; ++k) {
    if (k < rem) {
      hf2 x01 = __builtin_bit_cast(hf2, s8[k].x);
      hf2 x23 = __builtin_bit_cast(hf2, s8[k].y);
      hf2 x5{__builtin_bit_cast(_Float16, s1[k]), (_Float16)0.f};
      float T = fdot2(habs2(x01 + xr01), av01,
                fdot2(habs2(x23 + xr23), av23,
                fdot2(habs2(x5 + xr5), av5, 0.f)));
      T += __shfl_xor(T, 1, 64);
      T += __shfl_xor(T, 2, 64);
      T += __shfl_xor(T, 4, 64);
      T += __shfl_xor(T, 8, 64);
      float w = exp2f(fminf(T + sp[k] + prv, 80.f));
      den += w;
      acc[0] = fmaf(w, (float)x01[0], acc[0]);
      acc[1] = fmaf(w, (float)x01[1], acc[1]);
      acc[2] = fmaf(w, (float)x23[0], acc[2]);
      acc[3] = fmaf(w, (float)x23[1], acc[3]);
      acc[4] = fmaf(w, (float)x5[0], acc[4]);
    }
  }

  float inv = 1.f / (den + 1e-16f);
  union { v2h h[2]; u16x4 o; } u;
  u.h[0] = pkrtz(fmaf(acc[0], inv, bp4.x), fmaf(acc[1], inv, bp4.y));
  u.h[1] = pkrtz(fmaf(acc[2], inv, bp4.z), fmaf(acc[3], inv, bp4.w));
  *(u16x4*)(out + (size_t)d * NPERM + lane * 4) = u.o;
  out[(size_t)d * NPERM + 256 + lane] = f2h(fmaf(acc[4], inv, bp5));
}

// ======================= BatchNorm (permuted f16 h) =======================
__global__ __launch_bounds__(320) void k_bn_reduce(const ushort* __restrict__ h,
                                                   float* __restrict__ colsum,
                                                   float* __restrict__ colsq,
                                                   int n, int rows_per_block) {
  int c = threadIdx.x;
  int r0 = blockIdx.x * rows_per_block;
  int r1 = min(r0 + rows_per_block, n);
  float s = 0.f, s2 = 0.f;
  for (int r = r0; r < r1; ++r) {
    float v = h2f(h[(size_t)r * NPERM + c]);
    s += v;
    s2 += v * v;
  }
  atomicAdd(&colsum[c], s);
  atomicAdd(&colsq[c], s2);
}

__global__ void k_bn_coef(float* __restrict__ colsum, float* __restrict__ colsq,
                          const float* __restrict__ gp, const float* __restrict__ bp,
                          float invN) {
  int c = threadIdx.x + blockIdx.x * blockDim.x;
  if (c >= NPERM) return;
  float mu = colsum[c] * invN;
  float var = colsq[c] * invN - mu * mu;
  float scale = rsqrtf(var + BN_EPS) * gp[c];
  colsum[c] = scale;
  colsq[c] = bp[c] - mu * scale;
}

// BN + leaky-relu: h f16 -> abuf f16 (layer-2 GEMM A)
__global__ void k_bn_apply_bf(const ushort* __restrict__ h,
                              const float* __restrict__ scale,
                              const float* __restrict__ shift,
                              ushort* __restrict__ outb, int total8) {
  int i = blockIdx.x * blockDim.x + threadIdx.x;
  if (i >= total8) return;
  int cg = i - (i / 40) * 40;
  u16x8 v = *(const u16x8*)(h + (size_t)i * 8);
  float f[8];
#pragma unroll
  for (int k = 0; k < 8; ++k) {
    int c = cg * 8 + k;
    float t = fmaf(h2f(v[k]), scale[c], shift[c]);
    f[k] = (t > 0.f) ? t : 0.01f * t;
  }
  union { v2h h4[4]; u16x8 o; } u;
#pragma unroll
  for (int k = 0; k < 4; ++k)
    u.h4[k] = pkrtz(f[2 * k], f[2 * k + 1]);
  *(u16x8*)(outb + (size_t)i * 8) = u.o;
}

// ======================= fused BN + leaky-relu + classifier =======================
__global__ __launch_bounds__(256) void k_bn_classifier(
    const ushort* __restrict__ h, const float* __restrict__ scale,
    const float* __restrict__ shift, const float* __restrict__ wc0,
    const float* __restrict__ wc1, const float* __restrict__ bc,
    float* __restrict__ out, int n) {
  int wave = threadIdx.x >> 6, lane = threadIdx.x & 63;
  int r = blockIdx.x * 4 + wave;
  if (r >= n) return;
  float a0 = 0.f, a1 = 0.f;
#pragma unroll
  for (int k = 0; k < SLOTS; ++k) {
    int slot = lane + 64 * k;
    float v = fmaf(h2f(h[(size_t)r * NPERM + slot]), scale[slot], shift[slot]);
    v = (v > 0.f) ? v : 0.01f * v;
    a0 = fmaf(v, wc0[slot], a0);
    a1 = fmaf(v, wc1[slot], a1);
  }
#pragma unroll
  for (int off = 32; off > 0; off >>= 1) {
    a0 += __shfl_xor(a0, off, 64);
    a1 += __shfl_xor(a1, off, 64);
  }
  if (lane == 0) {
    out[(size_t)2 * r] = a0 + bc[0];
    out[(size_t)2 * r + 1] = a1 + bc[1];
  }
}

// ======================= host launch =======================
extern "C" void kernel_launch(void* const* d_in, const int* in_sizes, int n_in,
                              void* d_out, int out_size, void* d_ws, size_t ws_size,
                              hipStream_t stream) {
  const float* x      = (const float*)d_in[0];
  const int*   eidx   = (const int*)d_in[1];
  const float* Wl1    = (const float*)d_in[2];
  const float* bl1    = (const float*)d_in[3];
  const float* Wr1    = (const float*)d_in[4];
  const float* br1    = (const float*)d_in[5];
  const float* att1   = (const float*)d_in[6];
  const float* b1     = (const float*)d_in[7];
  const float* Wl2    = (const float*)d_in[8];
  const float* bl2    = (const float*)d_in[9];
  const float* Wr2    = (const float*)d_in[10];
  const float* br2    = (const float*)d_in[11];
  const float* att2   = (const float*)d_in[12];
  const float* b2     = (const float*)d_in[13];
  const float* gamma  = (const float*)d_in[14];
  const float* beta   = (const float*)d_in[15];
  const float* Wc     = (const float*)d_in[16];
  const float* bc     = (const float*)d_in[17];
  float* out = (float*)d_out;

  const int FIN = 128;
  const int N = in_sizes[0] / FIN;   // 50000
  const int E = in_sizes[1] / 2;     // 800000

  const int* src = eidx;
  const int* dst = eidx + E;

  // ---- workspace layout (16B-aligned) ----
  ushort* h      = (ushort*)d_ws;                 // N*320 f16 permuted
  ushort* xl     = h + (size_t)N * NPERM;         // N*320
  ushort* xr     = xl + (size_t)N * NPERM;        // N*320
  ushort* abuf   = xr + (size_t)N * NPERM;        // N*320 (layer-2 GEMM A)
  ushort* wb     = abuf + (size_t)N * NPERM;      // 640*320 combined Wl|Wr
  float* pb      = (float*)(wb + (size_t)2 * NPERM * NPERM);  // 640
  float* vecp    = pb + 2 * NPERM;                // 8*320
  float* pl      = vecp + 8 * NPERM;              // N*4
  float* colsum  = pl + (size_t)N * NHEAD;        // 320 (-> scale)
  float* colsq   = colsum + NPERM;                // 320 (-> shift)
  int* deg       = (int*)(colsq + NPERM);
  int* row_ptr   = deg + N;                       // N+1
  int* cursor    = row_ptr + N + 1;
  int* bsum      = cursor + N;                    // 256
  int* boff      = bsum + 256;                    // 256
  int* csr_src   = boff + 256;                    // E

  const int G = (N + 255) / 256;
  const int EB = (E + 255) / 256;
  const int AGGB = (N + 3) / 4;
  const int MITERS = (N + 255) / 256;
  const int GEMMB = 512;

  const float* att1p = vecp;
  const float* b1p   = vecp + NPERM;
  const float* att2p = vecp + 2 * NPERM;
  const float* b2p   = vecp + 3 * NPERM;
  const float* gp    = vecp + 4 * NPERM;
  const float* btp   = vecp + 5 * NPERM;
  const float* wc0   = vecp + 6 * NPERM;
  const float* wc1   = vecp + 7 * NPERM;

  // ---- CSR build ----
  hipMemsetAsync(deg, 0, (size_t)N * sizeof(int), stream);
  k_hist<<<EB, 256, 0, stream>>>(dst, deg, E);
  k_block_sum<<<G, 256, 0, stream>>>(deg, bsum, N);
  k_scan_small<<<1, 256, 0, stream>>>(bsum, boff, G);
  k_scan_final<<<G, 256, 0, stream>>>(deg, boff, row_ptr, cursor, N, E);
  k_csr_fill<<<EB, 256, 0, stream>>>(src, dst, cursor, csr_src, E);

  k_vecperm<<<8, NPERM, 0, stream>>>(att1, b1, att2, b2, gamma, beta, Wc, vecp);

  // ---- layer 1 (A = x fp32, converted in-register) ----
  k_wperm<<<NPERM, FIN, 0, stream>>>(Wl1, bl1, wb, pb, FIN, FIN, 0);
  k_wperm<<<NPERM, FIN, 0, stream>>>(Wr1, br1, wb + (size_t)NPERM * FIN, pb + NPERM,
                                     FIN, FIN, 0);
  k_gemm_blds<FIN, true><<<GEMMB, 256, 0, stream>>>((const void*)x, wb, pb,
                                                    xl, xr, N, MITERS);
  k_pre<<<AGGB, 256, 0, stream>>>(xl, att1p, pl, N);
  k_agg<<<AGGB, 256, 0, stream>>>(xl, xr, pl, csr_src, row_ptr, att1p, b1p, h, N);

  const int RPB = (N + 255) / 256;
  hipMemsetAsync(colsum, 0, 2 * NPERM * sizeof(float), stream);
  k_bn_reduce<<<256, NPERM, 0, stream>>>(h, colsum, colsq, N, RPB);
  k_bn_coef<<<2, 160, 0, stream>>>(colsum, colsq, gp, btp, 1.f / (float)N);
  k_bn_apply_bf<<<(N * 40 + 255) / 256, 256, 0, stream>>>(h, colsum, colsq, abuf,
                                                          N * 40);

  // ---- layer 2 (K permuted to match permuted-native abuf) ----
  k_wperm<<<NPERM, NPERM, 0, stream>>>(Wl2, bl2, wb, pb, HCDIM, NPERM, 1);
  k_wperm<<<NPERM, NPERM, 0, stream>>>(Wr2, br2, wb + (size_t)NPERM * NPERM,
                                       pb + NPERM, HCDIM, NPERM, 1);
  k_gemm_blds<NPERM, false><<<GEMMB, 256, 0, stream>>>((const void*)abuf, wb, pb,
                                                       xl, xr, N, MITERS);
  k_pre<<<AGGB, 256, 0, stream>>>(xl, att2p, pl, N);
  k_agg<<<AGGB, 256, 0, stream>>>(xl, xr, pl, csr_src, row_ptr, att2p, b2p, h, N);

  hipMemsetAsync(colsum, 0, 2 * NPERM * sizeof(float), stream);
  k_bn_reduce<<<256, NPERM, 0, stream>>>(h, colsum, colsq, N, RPB);
  k_bn_coef<<<2, 160, 0, stream>>>(colsum, colsq, gp, btp, 1.f / (float)N);

  // ---- fused BN + classifier ----
  k_bn_classifier<<<AGGB, 256, 0, stream>>>(h, colsum, colsq, wc0, wc1, bc, out, N);
}